// Round 1
// baseline (2103.666 us; speedup 1.0000x reference)
//
#include <hip/hip_runtime.h>
#include <math.h>

#define B_ 4
#define T_ 2048
#define D_ 1024
#define H_ 16
#define HD_ 64
#define BT_ (B_ * T_)

// ---------------------------------------------------------------------------
// Kernel 1: QKV projection.  q[b,h,t,k] = sum_d x[b,t,d] * Wz[h,d,k]
// grid (BT/64, H, 3), block 256.  64x64 output tile, K=1024 in steps of 16.
// ---------------------------------------------------------------------------
__global__ __launch_bounds__(256) void qkv_kernel(
    const float* __restrict__ x,
    const float* __restrict__ Wq, const float* __restrict__ Wk,
    const float* __restrict__ Wv, float* __restrict__ qkv_ws) {
  const int m0 = blockIdx.x * 64;   // row tile over (b,t)
  const int h  = blockIdx.y;
  const int z  = blockIdx.z;        // 0=Q 1=K 2=V
  const float* W = (z == 0 ? Wq : (z == 1 ? Wk : Wv)) + (size_t)h * D_ * HD_;
  float* out = qkv_ws + (size_t)z * ((size_t)B_ * H_ * T_ * HD_);

  __shared__ float As[16][68];  // As[k][m]  (transposed store; 68-pad => 2-way reads, free)
  __shared__ float Bs[16][68];  // Bs[k][n]

  const int tid = threadIdx.x;
  const int tx = tid & 15, ty = tid >> 4;
  const int lr = tid >> 2;          // 0..63 A-row to load
  const int lc = (tid & 3) * 4;     // A k-chunk
  const int wr = tid >> 4;          // 0..15 W-row (k) to load
  const int wc = (tid & 15) * 4;    // W col

  float acc[4][4] = {{0.f, 0.f, 0.f, 0.f}, {0.f, 0.f, 0.f, 0.f},
                     {0.f, 0.f, 0.f, 0.f}, {0.f, 0.f, 0.f, 0.f}};

  for (int k0 = 0; k0 < D_; k0 += 16) {
    float4 a4 = *(const float4*)(x + (size_t)(m0 + lr) * D_ + k0 + lc);
    As[lc + 0][lr] = a4.x; As[lc + 1][lr] = a4.y;
    As[lc + 2][lr] = a4.z; As[lc + 3][lr] = a4.w;
    float4 b4 = *(const float4*)(W + (size_t)(k0 + wr) * HD_ + wc);
    *(float4*)&Bs[wr][wc] = b4;
    __syncthreads();
#pragma unroll
    for (int kk = 0; kk < 16; ++kk) {
      float4 av = *(const float4*)&As[kk][ty * 4];
      float4 bv = *(const float4*)&Bs[kk][tx * 4];
      float aa[4] = {av.x, av.y, av.z, av.w};
      float bb[4] = {bv.x, bv.y, bv.z, bv.w};
#pragma unroll
      for (int i = 0; i < 4; ++i)
#pragma unroll
        for (int j = 0; j < 4; ++j)
          acc[i][j] = fmaf(aa[i], bb[j], acc[i][j]);
    }
    __syncthreads();
  }

#pragma unroll
  for (int i = 0; i < 4; ++i) {
    const int mrow = m0 + ty * 4 + i;
    const int bb = mrow / T_;
    const int tt = mrow % T_;
    float4 t = make_float4(acc[i][0], acc[i][1], acc[i][2], acc[i][3]);
    *(float4*)(out + ((size_t)(bb * H_ + h) * T_ + tt) * HD_ + tx * 4) = t;
  }
}

// ---------------------------------------------------------------------------
// Kernel 2: flash attention per (b,h).  64 q-rows per block, 256 threads.
// Softmax state (m,l) lives in registers: each row is owned by 16 lanes of
// one wave -> __shfl_xor reductions, no LDS round trip.
// LDS: Qs(scaled) + KP (K^T tile, reused for P) + Vs = 51 KB.
// ---------------------------------------------------------------------------
__global__ __launch_bounds__(256) void attn_kernel(
    const float* __restrict__ qkv_ws, float* __restrict__ concat) {
  const int q0 = blockIdx.x * 64;
  const int h  = blockIdx.y;
  const int b  = blockIdx.z;
  const size_t QSZ = (size_t)B_ * H_ * T_ * HD_;
  const size_t base = ((size_t)(b * H_ + h) * T_) * HD_;
  const float* Q = qkv_ws + base;
  const float* K = qkv_ws + QSZ + base;
  const float* V = qkv_ws + 2 * QSZ + base;

  __shared__ float Qs[64][68];  // [row][k], pre-scaled by 1/sqrt(HD)
  __shared__ float KP[64][68];  // K^T tile [k][key], then P tile [row][key]
  __shared__ float Vs[64][68];  // [key][hd]

  const int tid = threadIdx.x;
  const int tx = tid & 15, ty = tid >> 4;
  const int lr = tid >> 2;          // 0..63
  const int lc0 = (tid & 3) * 16;

#pragma unroll
  for (int c = 0; c < 16; c += 4) {
    float4 t = *(const float4*)(Q + (size_t)(q0 + lr) * HD_ + lc0 + c);
    t.x *= 0.125f; t.y *= 0.125f; t.z *= 0.125f; t.w *= 0.125f;
    *(float4*)&Qs[lr][lc0 + c] = t;
  }

  float m[4], l[4], o[4][4];
#pragma unroll
  for (int i = 0; i < 4; ++i) {
    m[i] = -INFINITY; l[i] = 0.f;
#pragma unroll
    for (int j = 0; j < 4; ++j) o[i][j] = 0.f;
  }
  __syncthreads();

  for (int kt = 0; kt < T_; kt += 64) {
    // stage K^T (scatter) and V (natural) tiles
#pragma unroll
    for (int c = 0; c < 16; c += 4) {
      float4 kv = *(const float4*)(K + (size_t)(kt + lr) * HD_ + lc0 + c);
      KP[lc0 + c + 0][lr] = kv.x; KP[lc0 + c + 1][lr] = kv.y;
      KP[lc0 + c + 2][lr] = kv.z; KP[lc0 + c + 3][lr] = kv.w;
      float4 vv = *(const float4*)(V + (size_t)(kt + lr) * HD_ + lc0 + c);
      *(float4*)&Vs[lr][lc0 + c] = vv;
    }
    __syncthreads();

    // S = Qs * K^T  (64x64, K=64)
    float s[4][4] = {{0.f, 0.f, 0.f, 0.f}, {0.f, 0.f, 0.f, 0.f},
                     {0.f, 0.f, 0.f, 0.f}, {0.f, 0.f, 0.f, 0.f}};
    for (int kk = 0; kk < 64; kk += 4) {
      float ka[4][4];
#pragma unroll
      for (int mm = 0; mm < 4; ++mm) {
        float4 t = *(const float4*)&KP[kk + mm][tx * 4];
        ka[mm][0] = t.x; ka[mm][1] = t.y; ka[mm][2] = t.z; ka[mm][3] = t.w;
      }
#pragma unroll
      for (int i = 0; i < 4; ++i) {
        float4 t = *(const float4*)&Qs[ty * 4 + i][kk];
        float qa[4] = {t.x, t.y, t.z, t.w};
#pragma unroll
        for (int mm = 0; mm < 4; ++mm) {
          s[i][0] = fmaf(qa[mm], ka[mm][0], s[i][0]);
          s[i][1] = fmaf(qa[mm], ka[mm][1], s[i][1]);
          s[i][2] = fmaf(qa[mm], ka[mm][2], s[i][2]);
          s[i][3] = fmaf(qa[mm], ka[mm][3], s[i][3]);
        }
      }
    }
    __syncthreads();  // done reading KP as K^T

    // online softmax; write P into KP
#pragma unroll
    for (int i = 0; i < 4; ++i) {
      float rm = fmaxf(fmaxf(s[i][0], s[i][1]), fmaxf(s[i][2], s[i][3]));
#pragma unroll
      for (int off = 1; off < 16; off <<= 1)
        rm = fmaxf(rm, __shfl_xor(rm, off));
      const float mn = fmaxf(m[i], rm);
      const float al = __expf(m[i] - mn);   // first tile: exp(-inf)=0
      float rs = 0.f;
#pragma unroll
      for (int j = 0; j < 4; ++j) {
        s[i][j] = __expf(s[i][j] - mn);
        rs += s[i][j];
      }
#pragma unroll
      for (int off = 1; off < 16; off <<= 1)
        rs += __shfl_xor(rs, off);
      m[i] = mn;
      l[i] = l[i] * al + rs;
#pragma unroll
      for (int j = 0; j < 4; ++j) o[i][j] *= al;
      *(float4*)&KP[ty * 4 + i][tx * 4] =
          make_float4(s[i][0], s[i][1], s[i][2], s[i][3]);
    }
    __syncthreads();

    // O += P * V  (64x64, K=64 keys)
    for (int kk = 0; kk < 64; kk += 4) {
      float va[4][4];
#pragma unroll
      for (int mm = 0; mm < 4; ++mm) {
        float4 t = *(const float4*)&Vs[kk + mm][tx * 4];
        va[mm][0] = t.x; va[mm][1] = t.y; va[mm][2] = t.z; va[mm][3] = t.w;
      }
#pragma unroll
      for (int i = 0; i < 4; ++i) {
        float4 t = *(const float4*)&KP[ty * 4 + i][kk];
        float pa[4] = {t.x, t.y, t.z, t.w};
#pragma unroll
        for (int mm = 0; mm < 4; ++mm) {
          o[i][0] = fmaf(pa[mm], va[mm][0], o[i][0]);
          o[i][1] = fmaf(pa[mm], va[mm][1], o[i][1]);
          o[i][2] = fmaf(pa[mm], va[mm][2], o[i][2]);
          o[i][3] = fmaf(pa[mm], va[mm][3], o[i][3]);
        }
      }
    }
    __syncthreads();  // protect KP/Vs before next tile's staging
  }

  // normalize + write concat[b, t, h*HD + c]
#pragma unroll
  for (int i = 0; i < 4; ++i) {
    const float inv = 1.f / l[i];
    const int row = q0 + ty * 4 + i;
    float4 t = make_float4(o[i][0] * inv, o[i][1] * inv,
                           o[i][2] * inv, o[i][3] * inv);
    *(float4*)(concat + (size_t)(b * T_ + row) * D_ + h * HD_ + tx * 4) = t;
  }
}

// ---------------------------------------------------------------------------
// Kernel 3: output projection.  out[m,n] = sum_e concat[m,e] * Wo[n,e]
// grid (BT/64, D/64), block 256.
// ---------------------------------------------------------------------------
__global__ __launch_bounds__(256) void oproj_kernel(
    const float* __restrict__ A, const float* __restrict__ Wo,
    float* __restrict__ out) {
  const int m0 = blockIdx.x * 64;
  const int n0 = blockIdx.y * 64;

  __shared__ float As[16][68];  // As[e][m]
  __shared__ float Bs[16][68];  // Bs[e][n]

  const int tid = threadIdx.x;
  const int tx = tid & 15, ty = tid >> 4;
  const int lr = tid >> 2;
  const int lc = (tid & 3) * 4;

  float acc[4][4] = {{0.f, 0.f, 0.f, 0.f}, {0.f, 0.f, 0.f, 0.f},
                     {0.f, 0.f, 0.f, 0.f}, {0.f, 0.f, 0.f, 0.f}};

  for (int k0 = 0; k0 < D_; k0 += 16) {
    float4 a4 = *(const float4*)(A + (size_t)(m0 + lr) * D_ + k0 + lc);
    As[lc + 0][lr] = a4.x; As[lc + 1][lr] = a4.y;
    As[lc + 2][lr] = a4.z; As[lc + 3][lr] = a4.w;
    float4 b4 = *(const float4*)(Wo + (size_t)(n0 + lr) * D_ + k0 + lc);
    Bs[lc + 0][lr] = b4.x; Bs[lc + 1][lr] = b4.y;
    Bs[lc + 2][lr] = b4.z; Bs[lc + 3][lr] = b4.w;
    __syncthreads();
#pragma unroll
    for (int kk = 0; kk < 16; ++kk) {
      float4 av = *(const float4*)&As[kk][ty * 4];
      float4 bv = *(const float4*)&Bs[kk][tx * 4];
      float aa[4] = {av.x, av.y, av.z, av.w};
      float bb[4] = {bv.x, bv.y, bv.z, bv.w};
#pragma unroll
      for (int i = 0; i < 4; ++i)
#pragma unroll
        for (int j = 0; j < 4; ++j)
          acc[i][j] = fmaf(aa[i], bb[j], acc[i][j]);
    }
    __syncthreads();
  }

#pragma unroll
  for (int i = 0; i < 4; ++i) {
    const int mrow = m0 + ty * 4 + i;
    float4 t = make_float4(acc[i][0], acc[i][1], acc[i][2], acc[i][3]);
    *(float4*)(out + (size_t)mrow * D_ + n0 + tx * 4) = t;
  }
}

// ---------------------------------------------------------------------------
extern "C" void kernel_launch(void* const* d_in, const int* in_sizes, int n_in,
                              void* d_out, int out_size, void* d_ws,
                              size_t ws_size, hipStream_t stream) {
  const float* x  = (const float*)d_in[0];
  const float* Wq = (const float*)d_in[1];
  const float* Wk = (const float*)d_in[2];
  const float* Wv = (const float*)d_in[3];
  const float* Wo = (const float*)d_in[4];
  float* ws  = (float*)d_ws;
  float* out = (float*)d_out;

  const size_t QSZ = (size_t)B_ * H_ * T_ * HD_;  // 8,388,608 floats
  float* concat = ws + 3 * QSZ;                   // total ws use: 128 MiB

  qkv_kernel<<<dim3(BT_ / 64, H_, 3), 256, 0, stream>>>(x, Wq, Wk, Wv, ws);
  attn_kernel<<<dim3(T_ / 64, H_, B_), 256, 0, stream>>>(ws, concat);
  oproj_kernel<<<dim3(BT_ / 64, D_ / 64), 256, 0, stream>>>(concat, Wo, out);
}

// Round 2
// 479.125 us; speedup vs baseline: 4.3906x; 4.3906x over previous
//
#include <hip/hip_runtime.h>
#include <math.h>

#define B_ 4
#define T_ 2048
#define D_ 1024
#define H_ 16
#define HD_ 64
#define BT_ (B_ * T_)

typedef __attribute__((ext_vector_type(8))) short bf16x8;
typedef __attribute__((ext_vector_type(4))) float f32x4;
typedef __attribute__((ext_vector_type(4))) unsigned int u32x4;
typedef unsigned short u16;
typedef unsigned int u32;

// ---- bf16 helpers (RNE, bit-ops only; inputs finite) ----------------------
__device__ __forceinline__ u16 f2bf(float f) {
  u32 u = __float_as_uint(f);
  u32 r = (u + 0x7FFFu + ((u >> 16) & 1u)) >> 16;
  return (u16)r;
}
__device__ __forceinline__ float bf2f(u16 b) {
  return __uint_as_float(((u32)b) << 16);
}

// async global->LDS, 16B per lane; dest = wave-uniform base + lane*16
__device__ __forceinline__ void gload16(const u16* g, u16* l) {
  __builtin_amdgcn_global_load_lds(
      (const __attribute__((address_space(1))) unsigned int*)g,
      (__attribute__((address_space(3))) unsigned int*)l, 16, 0, 0);
}

// ---------------------------------------------------------------------------
// convert_flat: fp32 -> (hi, lo) bf16 split.  n4 = count/4.
// ---------------------------------------------------------------------------
__global__ __launch_bounds__(256) void convert_flat(
    const float* __restrict__ src, u16* __restrict__ hi, u16* __restrict__ lo,
    int n4) {
  int i = blockIdx.x * 256 + threadIdx.x;
  const int stride = gridDim.x * 256;
  for (; i < n4; i += stride) {
    float4 v = ((const float4*)src)[i];
    ushort4 h, l;
    h.x = f2bf(v.x); l.x = f2bf(v.x - bf2f(h.x));
    h.y = f2bf(v.y); l.y = f2bf(v.y - bf2f(h.y));
    h.z = f2bf(v.z); l.z = f2bf(v.z - bf2f(h.z));
    h.w = f2bf(v.w); l.w = f2bf(v.w - bf2f(h.w));
    ((ushort4*)hi)[i] = h;
    ((ushort4*)lo)[i] = l;
  }
}

// ---------------------------------------------------------------------------
// convert_wt: Wq/Wk/Wv [h][d][kk] fp32 -> Wt_hi/lo [z][h][kk][d] bf16 (transposed)
// grid (D/64, H, 3), block 256.
// ---------------------------------------------------------------------------
__global__ __launch_bounds__(256) void convert_wt(
    const float* __restrict__ Wq, const float* __restrict__ Wk,
    const float* __restrict__ Wv, u16* __restrict__ wth,
    u16* __restrict__ wtl) {
  const int d0 = blockIdx.x * 64;
  const int h = blockIdx.y;
  const int z = blockIdx.z;
  const float* W = (z == 0 ? Wq : (z == 1 ? Wk : Wv)) + (size_t)h * D_ * HD_;
  __shared__ float Tl[64][65];
  const int tid = threadIdx.x;
  const int r = tid >> 2;           // 0..63
  const int c0 = (tid & 3) * 16;
#pragma unroll
  for (int j = 0; j < 16; j += 4) {
    float4 v = *(const float4*)(W + (size_t)(d0 + r) * HD_ + c0 + j);
    Tl[c0 + j + 0][r] = v.x; Tl[c0 + j + 1][r] = v.y;
    Tl[c0 + j + 2][r] = v.z; Tl[c0 + j + 3][r] = v.w;
  }
  __syncthreads();
  // write row kk=r of Wt: 16 d-values
  u16 hb[16], lb[16];
#pragma unroll
  for (int j = 0; j < 16; ++j) {
    float v = Tl[r][c0 + j];
    u16 hh = f2bf(v);
    hb[j] = hh; lb[j] = f2bf(v - bf2f(hh));
  }
  u16* oh = wth + (((size_t)z * H_ + h) * HD_ + r) * D_ + d0 + c0;
  u16* ol = wtl + (((size_t)z * H_ + h) * HD_ + r) * D_ + d0 + c0;
#pragma unroll
  for (int j = 0; j < 16; j += 4) {
    *(ushort4*)(oh + j) = make_ushort4(hb[j], hb[j + 1], hb[j + 2], hb[j + 3]);
    *(ushort4*)(ol + j) = make_ushort4(lb[j], lb[j + 1], lb[j + 2], lb[j + 3]);
  }
}

// ---------------------------------------------------------------------------
// qkv_mfma: 3-term split bf16 GEMM.  grid (BT/64, H, 3), 256 threads (4 waves).
// Outputs: Q (scaled 1/8) and K as bf16 [b,h,t,d]; V transposed [b,h,d,t].
// ---------------------------------------------------------------------------
__global__ __launch_bounds__(256) void qkv_mfma(
    const u16* __restrict__ xh, const u16* __restrict__ xl,
    const u16* __restrict__ wth, const u16* __restrict__ wtl,
    u16* __restrict__ Qb, u16* __restrict__ Kb, u16* __restrict__ Vtb) {
  const int m0 = blockIdx.x * 64;
  const int h = blockIdx.y;
  const int z = blockIdx.z;
  __shared__ __align__(16) u16 Xh[64 * 64];
  __shared__ __align__(16) u16 Xl[64 * 64];
  __shared__ __align__(16) u16 Wh[64 * 64];
  __shared__ __align__(16) u16 Wl[64 * 64];
  const int tid = threadIdx.x;
  const int lane = tid & 63, wave = tid >> 6;
  const int q = lane & 15, g = lane >> 4;
  const u16* wsh = wth + ((size_t)z * H_ + h) * HD_ * D_;
  const u16* wsl = wtl + ((size_t)z * H_ + h) * HD_ * D_;

  f32x4 acc[4];
#pragma unroll
  for (int t = 0; t < 4; ++t)
#pragma unroll
    for (int r = 0; r < 4; ++r) acc[t][r] = 0.f;

  for (int k0 = 0; k0 < D_; k0 += 64) {
#pragma unroll
    for (int c = 0; c < 2; ++c) {
      const int cc = wave * 2 + c;
      const int slot = cc * 64 + lane;
      const int row = slot >> 3, sb = slot & 7;
      const int so = (sb ^ (row & 7)) * 8;
      gload16(xh + (size_t)(m0 + row) * D_ + k0 + so, &Xh[cc * 512]);
      gload16(xl + (size_t)(m0 + row) * D_ + k0 + so, &Xl[cc * 512]);
      gload16(wsh + (size_t)row * D_ + k0 + so, &Wh[cc * 512]);
      gload16(wsl + (size_t)row * D_ + k0 + so, &Wl[cc * 512]);
    }
    __syncthreads();
#pragma unroll
    for (int ks = 0; ks < 2; ++ks) {
      const int arow = wave * 16 + q;
      const int ab = arow * 128 + (((g + ks * 4) ^ (arow & 7)) * 16);
      bf16x8 ah = *(const bf16x8*)((const char*)Xh + ab);
      bf16x8 al = *(const bf16x8*)((const char*)Xl + ab);
#pragma unroll
      for (int nt = 0; nt < 4; ++nt) {
        const int brow = nt * 16 + q;
        const int bb = brow * 128 + (((g + ks * 4) ^ (brow & 7)) * 16);
        bf16x8 bh = *(const bf16x8*)((const char*)Wh + bb);
        bf16x8 bl = *(const bf16x8*)((const char*)Wl + bb);
        acc[nt] = __builtin_amdgcn_mfma_f32_16x16x32_bf16(ah, bh, acc[nt], 0, 0, 0);
        acc[nt] = __builtin_amdgcn_mfma_f32_16x16x32_bf16(ah, bl, acc[nt], 0, 0, 0);
        acc[nt] = __builtin_amdgcn_mfma_f32_16x16x32_bf16(al, bh, acc[nt], 0, 0, 0);
      }
    }
    __syncthreads();
  }

  const int b = m0 / T_;
  const int t_base = (m0 % T_) + wave * 16 + g * 4;
  if (z < 2) {
    u16* dst = (z == 0 ? Qb : Kb) + (size_t)(b * H_ + h) * T_ * HD_;
    const float scale = (z == 0) ? 0.125f : 1.0f;
#pragma unroll
    for (int nt = 0; nt < 4; ++nt)
#pragma unroll
      for (int r = 0; r < 4; ++r)
        dst[(size_t)(t_base + r) * HD_ + nt * 16 + q] = f2bf(acc[nt][r] * scale);
  } else {
    u16* dst = Vtb + (size_t)(b * H_ + h) * HD_ * T_;
#pragma unroll
    for (int nt = 0; nt < 4; ++nt) {
      ushort4 v = make_ushort4(f2bf(acc[nt][0]), f2bf(acc[nt][1]),
                               f2bf(acc[nt][2]), f2bf(acc[nt][3]));
      *(ushort4*)(dst + (size_t)(nt * 16 + q) * T_ + t_base) = v;
    }
  }
}

// ---------------------------------------------------------------------------
// attn_mfma: flash attention, swapped-operand QK^T.  grid (T/64, H, B), 4 waves.
// Each wave owns 16 q-rows (q = lane&15); scores lane-local after mfma(K,Q).
// Writes concat as bf16 hi/lo for the split oproj.
// ---------------------------------------------------------------------------
__global__ __launch_bounds__(256) void attn_mfma(
    const u16* __restrict__ Qb, const u16* __restrict__ Kb,
    const u16* __restrict__ Vtb, u16* __restrict__ ch, u16* __restrict__ cl) {
  const int q0 = blockIdx.x * 64;
  const int h = blockIdx.y;
  const int b = blockIdx.z;
  __shared__ __align__(16) u16 Ks[64 * 64];  // [key][d] bf16, XOR swizzled
  __shared__ __align__(16) u16 Vs[64 * 64];  // [hd][key] bf16, XOR swizzled
  const int tid = threadIdx.x;
  const int lane = tid & 63, wave = tid >> 6;
  const int q = lane & 15, g = lane >> 4;

  const u16* Qg = Qb + ((size_t)(b * H_ + h) * T_ + q0 + wave * 16 + q) * HD_;
  const u16* Kg = Kb + (size_t)(b * H_ + h) * T_ * HD_;
  const u16* Vg = Vtb + (size_t)(b * H_ + h) * HD_ * T_;

  // Q B-fragments hoisted (col = q, k = d = g*8+j, +32 for ks=1)
  const bf16x8 qf0 = *(const bf16x8*)(Qg + g * 8);
  const bf16x8 qf1 = *(const bf16x8*)(Qg + 32 + g * 8);

  f32x4 ot[4];
#pragma unroll
  for (int t = 0; t < 4; ++t)
#pragma unroll
    for (int r = 0; r < 4; ++r) ot[t][r] = 0.f;
  float m_run = -INFINITY, l_run = 0.f;

  for (int kt = 0; kt < T_; kt += 64) {
#pragma unroll
    for (int c = 0; c < 2; ++c) {
      const int cc = wave * 2 + c;
      const int slot = cc * 64 + lane;
      const int row = slot >> 3, sb = slot & 7;
      const int so = (sb ^ (row & 7)) * 8;
      gload16(Kg + (size_t)(kt + row) * HD_ + so, &Ks[cc * 512]);
      gload16(Vg + (size_t)row * T_ + kt + so, &Vs[cc * 512]);
    }
    __syncthreads();

    // S^T tiles: st[t] holds keys t*16+g*4+r for q-col (lane&15)
    f32x4 st[4];
#pragma unroll
    for (int t = 0; t < 4; ++t)
#pragma unroll
      for (int r = 0; r < 4; ++r) st[t][r] = 0.f;
#pragma unroll
    for (int ks = 0; ks < 2; ++ks) {
      const bf16x8 qf = ks ? qf1 : qf0;
#pragma unroll
      for (int t = 0; t < 4; ++t) {
        const int row = t * 16 + q;
        const int byte = row * 128 + (((g + ks * 4) ^ (row & 7)) * 16);
        bf16x8 kf = *(const bf16x8*)((const char*)Ks + byte);
        st[t] = __builtin_amdgcn_mfma_f32_16x16x32_bf16(kf, qf, st[t], 0, 0, 0);
      }
    }

    // online softmax (scores already scaled: Q pre-scaled by 1/8)
    float mx = -INFINITY;
#pragma unroll
    for (int t = 0; t < 4; ++t)
#pragma unroll
      for (int r = 0; r < 4; ++r) mx = fmaxf(mx, st[t][r]);
    mx = fmaxf(mx, __shfl_xor(mx, 16));
    mx = fmaxf(mx, __shfl_xor(mx, 32));
    const float mnew = fmaxf(m_run, mx);
    const float al = __expf(m_run - mnew);
    float p[4][4];
    float rs = 0.f;
#pragma unroll
    for (int t = 0; t < 4; ++t)
#pragma unroll
      for (int r = 0; r < 4; ++r) {
        const float e = __expf(st[t][r] - mnew);
        p[t][r] = e;
        rs += e;
      }
    rs += __shfl_xor(rs, 16);
    rs += __shfl_xor(rs, 32);
    m_run = mnew;
    l_run = l_run * al + rs;
#pragma unroll
    for (int t = 0; t < 4; ++t)
#pragma unroll
      for (int r = 0; r < 4; ++r) ot[t][r] *= al;

    // pack P^T pairs: pk[t][i] = {p[t][2i] lo, p[t][2i+1] hi}
    u32 pk[4][2];
#pragma unroll
    for (int t = 0; t < 4; ++t)
#pragma unroll
      for (int i = 0; i < 2; ++i)
        pk[t][i] = (u32)f2bf(p[t][2 * i]) | ((u32)f2bf(p[t][2 * i + 1]) << 16);

    // PV: O^T += V^T * P^T.  B-frag word w needs keys ks*32+g*8+{2w,2w+1},
    // held at lane ((2g+(w>>1))&3)*16+q in tile ks*2+(g>>1), pair w&1.
#pragma unroll
    for (int ks = 0; ks < 2; ++ks) {
      u32 bw[4];
#pragma unroll
      for (int w = 0; w < 4; ++w) {
        const int srcl = ((2 * g + (w >> 1)) & 3) * 16 + q;
        const u32 lo = (u32)__shfl((int)pk[ks * 2][w & 1], srcl);
        const u32 hi2 = (u32)__shfl((int)pk[ks * 2 + 1][w & 1], srcl);
        bw[w] = (g >> 1) ? hi2 : lo;
      }
      u32x4 tmp = {bw[0], bw[1], bw[2], bw[3]};
      bf16x8 pf = __builtin_bit_cast(bf16x8, tmp);
#pragma unroll
      for (int t = 0; t < 4; ++t) {
        const int row = t * 16 + q;
        const int byte = row * 128 + (((g + ks * 4) ^ (row & 7)) * 16);
        bf16x8 vf = *(const bf16x8*)((const char*)Vs + byte);
        ot[t] = __builtin_amdgcn_mfma_f32_16x16x32_bf16(vf, pf, ot[t], 0, 0, 0);
      }
    }
    __syncthreads();
  }

  // epilogue: concat[b, q0+wave*16+q, h*64 + t*16 + g*4 + r] as hi/lo bf16
  const float inv = 1.f / l_run;
  const size_t rowbase =
      (size_t)(b * T_ + q0 + wave * 16 + q) * D_ + h * HD_;
#pragma unroll
  for (int t = 0; t < 4; ++t) {
    ushort4 vh, vl;
    float v0 = ot[t][0] * inv, v1 = ot[t][1] * inv;
    float v2 = ot[t][2] * inv, v3 = ot[t][3] * inv;
    vh = make_ushort4(f2bf(v0), f2bf(v1), f2bf(v2), f2bf(v3));
    vl = make_ushort4(f2bf(v0 - bf2f(vh.x)), f2bf(v1 - bf2f(vh.y)),
                      f2bf(v2 - bf2f(vh.z)), f2bf(v3 - bf2f(vh.w)));
    *(ushort4*)(ch + rowbase + t * 16 + g * 4) = vh;
    *(ushort4*)(cl + rowbase + t * 16 + g * 4) = vl;
  }
}

// ---------------------------------------------------------------------------
// oproj_mfma: out[m,n] = sum_e concat[m,e]*Wo[n,e], 3-term split bf16.
// grid (BT/64, D/64), 256 threads.  Wo natural layout is already [n][e].
// ---------------------------------------------------------------------------
__global__ __launch_bounds__(256) void oproj_mfma(
    const u16* __restrict__ ah_g, const u16* __restrict__ al_g,
    const u16* __restrict__ wh_g, const u16* __restrict__ wl_g,
    float* __restrict__ out) {
  const int m0 = blockIdx.x * 64;
  const int n0 = blockIdx.y * 64;
  __shared__ __align__(16) u16 Ah[64 * 64];
  __shared__ __align__(16) u16 Al[64 * 64];
  __shared__ __align__(16) u16 Bh[64 * 64];
  __shared__ __align__(16) u16 Bl[64 * 64];
  const int tid = threadIdx.x;
  const int lane = tid & 63, wave = tid >> 6;
  const int q = lane & 15, g = lane >> 4;

  f32x4 acc[4];
#pragma unroll
  for (int t = 0; t < 4; ++t)
#pragma unroll
    for (int r = 0; r < 4; ++r) acc[t][r] = 0.f;

  for (int k0 = 0; k0 < D_; k0 += 64) {
#pragma unroll
    for (int c = 0; c < 2; ++c) {
      const int cc = wave * 2 + c;
      const int slot = cc * 64 + lane;
      const int row = slot >> 3, sb = slot & 7;
      const int so = (sb ^ (row & 7)) * 8;
      gload16(ah_g + (size_t)(m0 + row) * D_ + k0 + so, &Ah[cc * 512]);
      gload16(al_g + (size_t)(m0 + row) * D_ + k0 + so, &Al[cc * 512]);
      gload16(wh_g + (size_t)(n0 + row) * D_ + k0 + so, &Bh[cc * 512]);
      gload16(wl_g + (size_t)(n0 + row) * D_ + k0 + so, &Bl[cc * 512]);
    }
    __syncthreads();
#pragma unroll
    for (int ks = 0; ks < 2; ++ks) {
      const int arow = wave * 16 + q;
      const int ab = arow * 128 + (((g + ks * 4) ^ (arow & 7)) * 16);
      bf16x8 ah = *(const bf16x8*)((const char*)Ah + ab);
      bf16x8 al = *(const bf16x8*)((const char*)Al + ab);
#pragma unroll
      for (int nt = 0; nt < 4; ++nt) {
        const int brow = nt * 16 + q;
        const int bb = brow * 128 + (((g + ks * 4) ^ (brow & 7)) * 16);
        bf16x8 bh = *(const bf16x8*)((const char*)Bh + bb);
        bf16x8 bl = *(const bf16x8*)((const char*)Bl + bb);
        acc[nt] = __builtin_amdgcn_mfma_f32_16x16x32_bf16(ah, bh, acc[nt], 0, 0, 0);
        acc[nt] = __builtin_amdgcn_mfma_f32_16x16x32_bf16(ah, bl, acc[nt], 0, 0, 0);
        acc[nt] = __builtin_amdgcn_mfma_f32_16x16x32_bf16(al, bh, acc[nt], 0, 0, 0);
      }
    }
    __syncthreads();
  }

  const int mrow = m0 + wave * 16 + g * 4;
#pragma unroll
  for (int nt = 0; nt < 4; ++nt)
#pragma unroll
    for (int r = 0; r < 4; ++r)
      out[(size_t)(mrow + r) * D_ + n0 + nt * 16 + q] = acc[nt][r];
}

// ---------------------------------------------------------------------------
extern "C" void kernel_launch(void* const* d_in, const int* in_sizes, int n_in,
                              void* d_out, int out_size, void* d_ws,
                              size_t ws_size, hipStream_t stream) {
  const float* x = (const float*)d_in[0];
  const float* Wq = (const float*)d_in[1];
  const float* Wk = (const float*)d_in[2];
  const float* Wv = (const float*)d_in[3];
  const float* Wo = (const float*)d_in[4];
  float* out = (float*)d_out;

  u16* ws16 = (u16*)d_ws;
  u16* x_hi = ws16;                      //  8,388,608
  u16* x_lo = ws16 + 8388608;
  u16* wt_hi = ws16 + 16777216;          //  3,145,728
  u16* wt_lo = ws16 + 19922944;
  u16* wo_hi = ws16 + 23068672;          //  1,048,576
  u16* wo_lo = ws16 + 24117248;
  u16* Qb = ws16 + 25165824;             //  8,388,608
  u16* Kb = ws16 + 33554432;
  u16* Vtb = ws16 + 41943040;            //  end @ 50,331,648 elems (~100 MB)
  u16* c_hi = x_hi;                      // reuse (x consumed before attn)
  u16* c_lo = x_lo;

  convert_flat<<<2048, 256, 0, stream>>>(x, x_hi, x_lo, BT_ * D_ / 4);
  convert_flat<<<1024, 256, 0, stream>>>(Wo, wo_hi, wo_lo, D_ * D_ / 4);
  convert_wt<<<dim3(D_ / 64, H_, 3), 256, 0, stream>>>(Wq, Wk, Wv, wt_hi, wt_lo);
  qkv_mfma<<<dim3(BT_ / 64, H_, 3), 256, 0, stream>>>(x_hi, x_lo, wt_hi, wt_lo,
                                                      Qb, Kb, Vtb);
  attn_mfma<<<dim3(T_ / 64, H_, B_), 256, 0, stream>>>(Qb, Kb, Vtb, c_hi, c_lo);
  oproj_mfma<<<dim3(BT_ / 64, D_ / 64), 256, 0, stream>>>(c_hi, c_lo, wo_hi,
                                                          wo_lo, out);
}

// Round 4
// 406.432 us; speedup vs baseline: 5.1759x; 1.1789x over previous
//
#include <hip/hip_runtime.h>
#include <math.h>

#define B_ 4
#define T_ 2048
#define D_ 1024
#define H_ 16
#define HD_ 64
#define BT_ (B_ * T_)

typedef __attribute__((ext_vector_type(8))) short bf16x8;
typedef __attribute__((ext_vector_type(4))) float f32x4;
typedef __attribute__((ext_vector_type(4))) unsigned int u32x4;
typedef unsigned short u16;
typedef unsigned int u32;

// ---- bf16 helpers (RNE, bit-ops only; inputs finite) ----------------------
__device__ __forceinline__ u16 f2bf(float f) {
  u32 u = __float_as_uint(f);
  u32 r = (u + 0x7FFFu + ((u >> 16) & 1u)) >> 16;
  return (u16)r;
}
__device__ __forceinline__ float bf2f(u16 b) {
  return __uint_as_float(((u32)b) << 16);
}
// pack 2 f32 -> 2 bf16 in one instruction (T12)
__device__ __forceinline__ u32 cvtpk(float lo, float hi) {
  u32 r;
  asm("v_cvt_pk_bf16_f32 %0, %1, %2" : "=v"(r) : "v"(lo), "v"(hi));
  return r;
}

// async global->LDS, 16B per lane; dest = wave-uniform base + lane*16
__device__ __forceinline__ void gload16(const u16* g, u16* l) {
  __builtin_amdgcn_global_load_lds(
      (const __attribute__((address_space(1))) unsigned int*)g,
      (__attribute__((address_space(3))) unsigned int*)l, 16, 0, 0);
}

// ---------------------------------------------------------------------------
// convert_flat: fp32 -> (hi, lo) bf16 split.  n4 = count/4.
// ---------------------------------------------------------------------------
__global__ __launch_bounds__(256) void convert_flat(
    const float* __restrict__ src, u16* __restrict__ hi, u16* __restrict__ lo,
    int n4) {
  int i = blockIdx.x * 256 + threadIdx.x;
  const int stride = gridDim.x * 256;
  for (; i < n4; i += stride) {
    float4 v = ((const float4*)src)[i];
    ushort4 h, l;
    h.x = f2bf(v.x); l.x = f2bf(v.x - bf2f(h.x));
    h.y = f2bf(v.y); l.y = f2bf(v.y - bf2f(h.y));
    h.z = f2bf(v.z); l.z = f2bf(v.z - bf2f(h.z));
    h.w = f2bf(v.w); l.w = f2bf(v.w - bf2f(h.w));
    ((ushort4*)hi)[i] = h;
    ((ushort4*)lo)[i] = l;
  }
}

// ---------------------------------------------------------------------------
// convert_wt: Wq/Wk/Wv [h][d][kk] fp32 -> Wt_hi/lo [z][h][kk][d] bf16
// ---------------------------------------------------------------------------
__global__ __launch_bounds__(256) void convert_wt(
    const float* __restrict__ Wq, const float* __restrict__ Wk,
    const float* __restrict__ Wv, u16* __restrict__ wth,
    u16* __restrict__ wtl) {
  const int d0 = blockIdx.x * 64;
  const int h = blockIdx.y;
  const int z = blockIdx.z;
  const float* W = (z == 0 ? Wq : (z == 1 ? Wk : Wv)) + (size_t)h * D_ * HD_;
  __shared__ float Tl[64][65];
  const int tid = threadIdx.x;
  const int r = tid >> 2;
  const int c0 = (tid & 3) * 16;
#pragma unroll
  for (int j = 0; j < 16; j += 4) {
    float4 v = *(const float4*)(W + (size_t)(d0 + r) * HD_ + c0 + j);
    Tl[c0 + j + 0][r] = v.x; Tl[c0 + j + 1][r] = v.y;
    Tl[c0 + j + 2][r] = v.z; Tl[c0 + j + 3][r] = v.w;
  }
  __syncthreads();
  u16 hb[16], lb[16];
#pragma unroll
  for (int j = 0; j < 16; ++j) {
    float v = Tl[r][c0 + j];
    u16 hh = f2bf(v);
    hb[j] = hh; lb[j] = f2bf(v - bf2f(hh));
  }
  u16* oh = wth + (((size_t)z * H_ + h) * HD_ + r) * D_ + d0 + c0;
  u16* ol = wtl + (((size_t)z * H_ + h) * HD_ + r) * D_ + d0 + c0;
#pragma unroll
  for (int j = 0; j < 16; j += 4) {
    *(ushort4*)(oh + j) = make_ushort4(hb[j], hb[j + 1], hb[j + 2], hb[j + 3]);
    *(ushort4*)(ol + j) = make_ushort4(lb[j], lb[j + 1], lb[j + 2], lb[j + 3]);
  }
}

// ---------------------------------------------------------------------------
// qkv_mfma: z-fused 3-term split GEMM.  grid (BT/128, H), 256 threads.
// 128x64 M-tile, X staged once, all 6 W tiles resident.  LDS = 80 KB.
// Q written pre-scaled by (1/8)*log2(e) for the exp2-domain softmax.
// ---------------------------------------------------------------------------
__global__ __launch_bounds__(256, 2) void qkv_mfma(
    const u16* __restrict__ xh, const u16* __restrict__ xl,
    const u16* __restrict__ wth, const u16* __restrict__ wtl,
    u16* __restrict__ Qb, u16* __restrict__ Kb, u16* __restrict__ Vtb) {
  const int m0 = blockIdx.x * 128;
  const int h = blockIdx.y;
  __shared__ __align__(16) u16 Xh[128 * 64];
  __shared__ __align__(16) u16 Xl[128 * 64];
  __shared__ __align__(16) u16 Wh[3 * 64 * 64];
  __shared__ __align__(16) u16 Wl[3 * 64 * 64];
  const int tid = threadIdx.x;
  const int lane = tid & 63, wave = tid >> 6;
  const int q = lane & 15, g = lane >> 4;

  f32x4 acc[3][2][4];
#pragma unroll
  for (int z = 0; z < 3; ++z)
#pragma unroll
    for (int mt = 0; mt < 2; ++mt)
#pragma unroll
      for (int nt = 0; nt < 4; ++nt)
#pragma unroll
        for (int r = 0; r < 4; ++r) acc[z][mt][nt][r] = 0.f;

  for (int k0 = 0; k0 < D_; k0 += 64) {
    // X tiles: 16 slots each of 1024B; wave handles 4
#pragma unroll
    for (int i = 0; i < 4; ++i) {
      const int l = wave * 4 + i;
      const int chunk = l * 64 + lane;
      const int row = chunk >> 3, sb = chunk & 7;
      const int so = (sb ^ (row & 7)) * 8;
      const size_t goff = (size_t)(m0 + row) * D_ + k0 + so;
      gload16(xh + goff, &Xh[l * 512]);
      gload16(xl + goff, &Xl[l * 512]);
    }
    // W tiles: 8 slots each; wave handles 2 per buffer
#pragma unroll
    for (int z = 0; z < 3; ++z)
#pragma unroll
      for (int i = 0; i < 2; ++i) {
        const int l = wave * 2 + i;
        const int chunk = l * 64 + lane;
        const int row = chunk >> 3, sb = chunk & 7;
        const int so = (sb ^ (row & 7)) * 8;
        const size_t goff = (((size_t)z * H_ + h) * HD_ + row) * D_ + k0 + so;
        gload16(wth + goff, &Wh[z * 4096 + l * 512]);
        gload16(wtl + goff, &Wl[z * 4096 + l * 512]);
      }
    __syncthreads();
#pragma unroll
    for (int ks = 0; ks < 2; ++ks) {
      bf16x8 axh[2], axl[2];
#pragma unroll
      for (int mt = 0; mt < 2; ++mt) {
        const int arow = wave * 32 + mt * 16 + q;
        const int ab = arow * 128 + (((g + ks * 4) ^ (arow & 7)) * 16);
        axh[mt] = *(const bf16x8*)((const char*)Xh + ab);
        axl[mt] = *(const bf16x8*)((const char*)Xl + ab);
      }
#pragma unroll
      for (int z = 0; z < 3; ++z)
#pragma unroll
        for (int nt = 0; nt < 4; ++nt) {
          const int brow = nt * 16 + q;
          const int bb =
              z * 8192 + brow * 128 + (((g + ks * 4) ^ (brow & 7)) * 16);
          bf16x8 bh = *(const bf16x8*)((const char*)Wh + bb);
          bf16x8 bl = *(const bf16x8*)((const char*)Wl + bb);
#pragma unroll
          for (int mt = 0; mt < 2; ++mt) {
            acc[z][mt][nt] = __builtin_amdgcn_mfma_f32_16x16x32_bf16(
                axh[mt], bh, acc[z][mt][nt], 0, 0, 0);
            acc[z][mt][nt] = __builtin_amdgcn_mfma_f32_16x16x32_bf16(
                axh[mt], bl, acc[z][mt][nt], 0, 0, 0);
            acc[z][mt][nt] = __builtin_amdgcn_mfma_f32_16x16x32_bf16(
                axl[mt], bh, acc[z][mt][nt], 0, 0, 0);
          }
        }
    }
    __syncthreads();
  }

  const int b = m0 / T_;
  const int trow0 = m0 % T_;
  const float QSC = 0.125f * 1.44269504f;  // fold log2(e) into Q
  u16* Qd = Qb + (size_t)(b * H_ + h) * T_ * HD_;
  u16* Kd = Kb + (size_t)(b * H_ + h) * T_ * HD_;
  u16* Vd = Vtb + (size_t)(b * H_ + h) * HD_ * T_;
#pragma unroll
  for (int mt = 0; mt < 2; ++mt) {
    const int t_base = trow0 + wave * 32 + mt * 16 + g * 4;
#pragma unroll
    for (int nt = 0; nt < 4; ++nt) {
      const int d = nt * 16 + q;
#pragma unroll
      for (int r = 0; r < 4; ++r) {
        Qd[(size_t)(t_base + r) * HD_ + d] = f2bf(acc[0][mt][nt][r] * QSC);
        Kd[(size_t)(t_base + r) * HD_ + d] = f2bf(acc[1][mt][nt][r]);
      }
      ushort4 v = make_ushort4(f2bf(acc[2][mt][nt][0]), f2bf(acc[2][mt][nt][1]),
                               f2bf(acc[2][mt][nt][2]), f2bf(acc[2][mt][nt][3]));
      *(ushort4*)(Vd + (size_t)d * T_ + t_base) = v;
    }
  }
}

// ---------------------------------------------------------------------------
// attn_mfma: flash attention, swapped QK^T, exp2-domain softmax, cvt_pk pack,
// defer-max (THR=8 log2), ones-row PV for the softmax denominator.
// ---------------------------------------------------------------------------
__global__ __launch_bounds__(256) void attn_mfma(
    const u16* __restrict__ Qb, const u16* __restrict__ Kb,
    const u16* __restrict__ Vtb, u16* __restrict__ ch, u16* __restrict__ cl) {
  const int q0 = blockIdx.x * 64;
  const int h = blockIdx.y;
  const int b = blockIdx.z;
  __shared__ __align__(16) u16 Ks[64 * 64];  // [key][d], XOR swizzled
  __shared__ __align__(16) u16 Vs[80 * 64];  // [hd][key] rows 0-63; row 64 = 1s
  const int tid = threadIdx.x;
  const int lane = tid & 63, wave = tid >> 6;
  const int q = lane & 15, g = lane >> 4;

  const u16* Qg = Qb + ((size_t)(b * H_ + h) * T_ + q0 + wave * 16 + q) * HD_;
  const u16* Kg = Kb + (size_t)(b * H_ + h) * T_ * HD_;
  const u16* Vg = Vtb + (size_t)(b * H_ + h) * HD_ * T_;

  // ones-row (row 64) + zero rows 65-79, written once
  {
    u16* vext = &Vs[64 * 64];
    for (int i = tid; i < 16 * 64; i += 256) vext[i] = (i < 64) ? 0x3F80 : 0;
  }

  const bf16x8 qf0 = *(const bf16x8*)(Qg + g * 8);
  const bf16x8 qf1 = *(const bf16x8*)(Qg + 32 + g * 8);

  f32x4 ot[4], ot4;
#pragma unroll
  for (int t = 0; t < 4; ++t)
#pragma unroll
    for (int r = 0; r < 4; ++r) ot[t][r] = 0.f;
#pragma unroll
  for (int r = 0; r < 4; ++r) ot4[r] = 0.f;
  float m_run = -INFINITY;

  for (int kt = 0; kt < T_; kt += 64) {
#pragma unroll
    for (int c = 0; c < 2; ++c) {
      const int cc = wave * 2 + c;
      const int slot = cc * 64 + lane;
      const int row = slot >> 3, sb = slot & 7;
      const int so = (sb ^ (row & 7)) * 8;
      gload16(Kg + (size_t)(kt + row) * HD_ + so, &Ks[cc * 512]);
      gload16(Vg + (size_t)row * T_ + kt + so, &Vs[cc * 512]);
    }
    __syncthreads();

    // S^T (log2 domain; Q pre-scaled by log2e/8)
    f32x4 st[4];
#pragma unroll
    for (int t = 0; t < 4; ++t)
#pragma unroll
      for (int r = 0; r < 4; ++r) st[t][r] = 0.f;
#pragma unroll
    for (int ks = 0; ks < 2; ++ks) {
      const bf16x8 qf = ks ? qf1 : qf0;
#pragma unroll
      for (int t = 0; t < 4; ++t) {
        const int row = t * 16 + q;
        const int byte = row * 128 + (((g + ks * 4) ^ (row & 7)) * 16);
        bf16x8 kf = *(const bf16x8*)((const char*)Ks + byte);
        st[t] = __builtin_amdgcn_mfma_f32_16x16x32_bf16(kf, qf, st[t], 0, 0, 0);
      }
    }

    // online softmax, exp2 domain, defer-max
    float mx = st[0][0];
#pragma unroll
    for (int t = 0; t < 4; ++t)
#pragma unroll
      for (int r = 0; r < 4; ++r) mx = fmaxf(mx, st[t][r]);
    mx = fmaxf(mx, __shfl_xor(mx, 16));
    mx = fmaxf(mx, __shfl_xor(mx, 32));
    if (!__all(mx <= m_run + 8.f)) {
      const float mnew = fmaxf(m_run, mx);
      const float al = __builtin_amdgcn_exp2f(m_run - mnew);
      m_run = mnew;
#pragma unroll
      for (int t = 0; t < 4; ++t)
#pragma unroll
        for (int r = 0; r < 4; ++r) ot[t][r] *= al;
#pragma unroll
      for (int r = 0; r < 4; ++r) ot4[r] *= al;
    }
    u32 pk[4][2];
#pragma unroll
    for (int t = 0; t < 4; ++t) {
      const float p0 = __builtin_amdgcn_exp2f(st[t][0] - m_run);
      const float p1 = __builtin_amdgcn_exp2f(st[t][1] - m_run);
      const float p2 = __builtin_amdgcn_exp2f(st[t][2] - m_run);
      const float p3 = __builtin_amdgcn_exp2f(st[t][3] - m_run);
      pk[t][0] = cvtpk(p0, p1);
      pk[t][1] = cvtpk(p2, p3);
    }

    // PV: O^T += V^T * P^T  (+ ones-row tile accumulating sum(P))
#pragma unroll
    for (int ks = 0; ks < 2; ++ks) {
      u32 bw[4];
#pragma unroll
      for (int w = 0; w < 4; ++w) {
        const int srcl = ((2 * g + (w >> 1)) & 3) * 16 + q;
        const u32 lo = (u32)__shfl((int)pk[ks * 2][w & 1], srcl);
        const u32 hi2 = (u32)__shfl((int)pk[ks * 2 + 1][w & 1], srcl);
        bw[w] = (g >> 1) ? hi2 : lo;
      }
      u32x4 tmp = {bw[0], bw[1], bw[2], bw[3]};
      bf16x8 pf = __builtin_bit_cast(bf16x8, tmp);
#pragma unroll
      for (int t = 0; t < 4; ++t) {
        const int row = t * 16 + q;
        const int byte = row * 128 + (((g + ks * 4) ^ (row & 7)) * 16);
        bf16x8 vf = *(const bf16x8*)((const char*)Vs + byte);
        ot[t] = __builtin_amdgcn_mfma_f32_16x16x32_bf16(vf, pf, ot[t], 0, 0, 0);
      }
      {
        const int row = 64 + q;
        const int byte = row * 128 + (((g + ks * 4) ^ (row & 7)) * 16);
        bf16x8 vf = *(const bf16x8*)((const char*)Vs + byte);
        ot4 = __builtin_amdgcn_mfma_f32_16x16x32_bf16(vf, pf, ot4, 0, 0, 0);
      }
    }
    __syncthreads();
  }

  // l for q-row q sits in lane q (ones-tile D row 64, reg 0)
  const float lsum = __shfl(ot4[0], q);
  const float inv = 1.f / lsum;
  const size_t rowbase = (size_t)(b * T_ + q0 + wave * 16 + q) * D_ + h * HD_;
#pragma unroll
  for (int t = 0; t < 4; ++t) {
    ushort4 vh, vl;
    float v0 = ot[t][0] * inv, v1 = ot[t][1] * inv;
    float v2 = ot[t][2] * inv, v3 = ot[t][3] * inv;
    vh = make_ushort4(f2bf(v0), f2bf(v1), f2bf(v2), f2bf(v3));
    vl = make_ushort4(f2bf(v0 - bf2f(vh.x)), f2bf(v1 - bf2f(vh.y)),
                      f2bf(v2 - bf2f(vh.z)), f2bf(v3 - bf2f(vh.w)));
    *(ushort4*)(ch + rowbase + t * 16 + g * 4) = vh;
    *(ushort4*)(cl + rowbase + t * 16 + g * 4) = vl;
  }
}

// ---------------------------------------------------------------------------
// oproj_mfma: 128x128 tile, 3-term split.  grid (BT/128, D/128) = 512 blocks.
// ---------------------------------------------------------------------------
__global__ __launch_bounds__(256, 2) void oproj_mfma(
    const u16* __restrict__ ah_g, const u16* __restrict__ al_g,
    const u16* __restrict__ wh_g, const u16* __restrict__ wl_g,
    float* __restrict__ out) {
  const int m0 = blockIdx.x * 128;
  const int n0 = blockIdx.y * 128;
  __shared__ __align__(16) u16 Ah[128 * 64];
  __shared__ __align__(16) u16 Al[128 * 64];
  __shared__ __align__(16) u16 Bh[128 * 64];
  __shared__ __align__(16) u16 Bl[128 * 64];
  const int tid = threadIdx.x;
  const int lane = tid & 63, wave = tid >> 6;
  const int q = lane & 15, g = lane >> 4;

  f32x4 acc[2][8];
#pragma unroll
  for (int mt = 0; mt < 2; ++mt)
#pragma unroll
    for (int nt = 0; nt < 8; ++nt)
#pragma unroll
      for (int r = 0; r < 4; ++r) acc[mt][nt][r] = 0.f;

  for (int k0 = 0; k0 < D_; k0 += 64) {
#pragma unroll
    for (int i = 0; i < 4; ++i) {
      const int l = wave * 4 + i;
      const int chunk = l * 64 + lane;
      const int row = chunk >> 3, sb = chunk & 7;
      const int so = (sb ^ (row & 7)) * 8;
      const size_t ga = (size_t)(m0 + row) * D_ + k0 + so;
      const size_t gb = (size_t)(n0 + row) * D_ + k0 + so;
      gload16(ah_g + ga, &Ah[l * 512]);
      gload16(al_g + ga, &Al[l * 512]);
      gload16(wh_g + gb, &Bh[l * 512]);
      gload16(wl_g + gb, &Bl[l * 512]);
    }
    __syncthreads();
#pragma unroll
    for (int ks = 0; ks < 2; ++ks) {
      bf16x8 axh[2], axl[2];
#pragma unroll
      for (int mt = 0; mt < 2; ++mt) {
        const int arow = wave * 32 + mt * 16 + q;
        const int ab = arow * 128 + (((g + ks * 4) ^ (arow & 7)) * 16);
        axh[mt] = *(const bf16x8*)((const char*)Ah + ab);
        axl[mt] = *(const bf16x8*)((const char*)Al + ab);
      }
#pragma unroll
      for (int nt = 0; nt < 8; ++nt) {
        const int brow = nt * 16 + q;
        const int bb = brow * 128 + (((g + ks * 4) ^ (brow & 7)) * 16);
        bf16x8 bh = *(const bf16x8*)((const char*)Bh + bb);
        bf16x8 bl = *(const bf16x8*)((const char*)Bl + bb);
#pragma unroll
        for (int mt = 0; mt < 2; ++mt) {
          acc[mt][nt] = __builtin_amdgcn_mfma_f32_16x16x32_bf16(
              axh[mt], bh, acc[mt][nt], 0, 0, 0);
          acc[mt][nt] = __builtin_amdgcn_mfma_f32_16x16x32_bf16(
              axh[mt], bl, acc[mt][nt], 0, 0, 0);
          acc[mt][nt] = __builtin_amdgcn_mfma_f32_16x16x32_bf16(
              axl[mt], bh, acc[mt][nt], 0, 0, 0);
        }
      }
    }
    __syncthreads();
  }

#pragma unroll
  for (int mt = 0; mt < 2; ++mt) {
    const int mrow = m0 + wave * 32 + mt * 16 + g * 4;
#pragma unroll
    for (int nt = 0; nt < 8; ++nt)
#pragma unroll
      for (int r = 0; r < 4; ++r)
        out[(size_t)(mrow + r) * D_ + n0 + nt * 16 + q] = acc[mt][nt][r];
  }
}

// ---------------------------------------------------------------------------
extern "C" void kernel_launch(void* const* d_in, const int* in_sizes, int n_in,
                              void* d_out, int out_size, void* d_ws,
                              size_t ws_size, hipStream_t stream) {
  const float* x = (const float*)d_in[0];
  const float* Wq = (const float*)d_in[1];
  const float* Wk = (const float*)d_in[2];
  const float* Wv = (const float*)d_in[3];
  const float* Wo = (const float*)d_in[4];
  float* out = (float*)d_out;

  u16* ws16 = (u16*)d_ws;
  u16* x_hi = ws16;                      //  8,388,608
  u16* x_lo = ws16 + 8388608;
  u16* wt_hi = ws16 + 16777216;          //  3,145,728
  u16* wt_lo = ws16 + 19922944;
  u16* wo_hi = ws16 + 23068672;          //  1,048,576
  u16* wo_lo = ws16 + 24117248;
  u16* Qb = ws16 + 25165824;             //  8,388,608
  u16* Kb = ws16 + 33554432;
  u16* Vtb = ws16 + 41943040;
  u16* c_hi = x_hi;                      // reuse (x consumed before attn)
  u16* c_lo = x_lo;

  convert_flat<<<2048, 256, 0, stream>>>(x, x_hi, x_lo, BT_ * D_ / 4);
  convert_flat<<<1024, 256, 0, stream>>>(Wo, wo_hi, wo_lo, D_ * D_ / 4);
  convert_wt<<<dim3(D_ / 64, H_, 3), 256, 0, stream>>>(Wq, Wk, Wv, wt_hi, wt_lo);
  qkv_mfma<<<dim3(BT_ / 128, H_), 256, 0, stream>>>(x_hi, x_lo, wt_hi, wt_lo,
                                                    Qb, Kb, Vtb);
  attn_mfma<<<dim3(T_ / 64, H_, B_), 256, 0, stream>>>(Qb, Kb, Vtb, c_hi, c_lo);
  oproj_mfma<<<dim3(BT_ / 128, D_ / 128), 256, 0, stream>>>(c_hi, c_lo, wo_hi,
                                                            wo_lo, out);
}

// Round 7
// 318.981 us; speedup vs baseline: 6.5950x; 1.2742x over previous
//
#include <hip/hip_runtime.h>
#include <math.h>

#define B_ 4
#define T_ 2048
#define D_ 1024
#define H_ 16
#define HD_ 64
#define BT_ (B_ * T_)

typedef __attribute__((ext_vector_type(8))) short bf16x8;
typedef __attribute__((ext_vector_type(8))) _Float16 f16x8;
typedef __attribute__((ext_vector_type(4))) float f32x4;
typedef __attribute__((ext_vector_type(4))) unsigned int u32x4;
typedef unsigned short u16;
typedef unsigned int u32;

// ---- bf16 helpers (RNE) ---------------------------------------------------
__device__ __forceinline__ u16 f2bf(float f) {
  u32 u = __float_as_uint(f);
  u32 r = (u + 0x7FFFu + ((u >> 16) & 1u)) >> 16;
  return (u16)r;
}
__device__ __forceinline__ float bf2f(u16 b) {
  return __uint_as_float(((u32)b) << 16);
}
// ---- fp16 helpers ---------------------------------------------------------
__device__ __forceinline__ u16 f2h(float f) {
  _Float16 h = (_Float16)f;
  return __builtin_bit_cast(u16, h);
}
__device__ __forceinline__ float h2f(u16 b) {
  return (float)__builtin_bit_cast(_Float16, b);
}
// pack 2 f32 -> 2 bf16 in one instruction (T12)
__device__ __forceinline__ u32 cvtpk(float lo, float hi) {
  u32 r;
  asm("v_cvt_pk_bf16_f32 %0, %1, %2" : "=v"(r) : "v"(lo), "v"(hi));
  return r;
}
// async global->LDS, 16B per lane; dest = wave-uniform base + lane*16
__device__ __forceinline__ void gload16(const u16* g, u16* l) {
  __builtin_amdgcn_global_load_lds(
      (const __attribute__((address_space(1))) unsigned int*)g,
      (__attribute__((address_space(3))) unsigned int*)l, 16, 0, 0);
}

// ---------------------------------------------------------------------------
// convert_f16: fp32 -> fp16 (single), flat.  n4 = count/4.
// ---------------------------------------------------------------------------
__global__ __launch_bounds__(256) void convert_f16(
    const float* __restrict__ src, u16* __restrict__ dst, int n4) {
  int i = blockIdx.x * 256 + threadIdx.x;
  const int stride = gridDim.x * 256;
  for (; i < n4; i += stride) {
    float4 v = ((const float4*)src)[i];
    ((ushort4*)dst)[i] = make_ushort4(f2h(v.x), f2h(v.y), f2h(v.z), f2h(v.w));
  }
}

// ---------------------------------------------------------------------------
// convert_wt: Wq/Wk/Wv [h][d][kk] fp32 -> wtf [z][h][kk][d] fp16 (transposed)
// ---------------------------------------------------------------------------
__global__ __launch_bounds__(256) void convert_wt(
    const float* __restrict__ Wq, const float* __restrict__ Wk,
    const float* __restrict__ Wv, u16* __restrict__ wtf) {
  const int d0 = blockIdx.x * 64;
  const int h = blockIdx.y;
  const int z = blockIdx.z;
  const float* W = (z == 0 ? Wq : (z == 1 ? Wk : Wv)) + (size_t)h * D_ * HD_;
  __shared__ float Tl[64][65];
  const int tid = threadIdx.x;
  const int r = tid >> 2;
  const int c0 = (tid & 3) * 16;
#pragma unroll
  for (int j = 0; j < 16; j += 4) {
    float4 v = *(const float4*)(W + (size_t)(d0 + r) * HD_ + c0 + j);
    Tl[c0 + j + 0][r] = v.x; Tl[c0 + j + 1][r] = v.y;
    Tl[c0 + j + 2][r] = v.z; Tl[c0 + j + 3][r] = v.w;
  }
  __syncthreads();
  u16* oh = wtf + (((size_t)z * H_ + h) * HD_ + r) * D_ + d0 + c0;
#pragma unroll
  for (int j = 0; j < 16; j += 4) {
    *(ushort4*)(oh + j) =
        make_ushort4(f2h(Tl[r][c0 + j]), f2h(Tl[r][c0 + j + 1]),
                     f2h(Tl[r][c0 + j + 2]), f2h(Tl[r][c0 + j + 3]));
  }
}

// ---------------------------------------------------------------------------
// qkv_mfma: single-pass fp16 GEMM, z-fused.  grid (BT/128, H), 256 threads.
// 128x64 M-tile; X staged once, 3 W tiles resident.  LDS = 40 KB.
// Outputs bf16: Q scaled by (1/8)*log2(e); K natural; V transposed.
// ---------------------------------------------------------------------------
__global__ __launch_bounds__(256, 2) void qkv_mfma(
    const u16* __restrict__ xf, const u16* __restrict__ wtf,
    u16* __restrict__ Qb, u16* __restrict__ Kb, u16* __restrict__ Vtb) {
  const int m0 = blockIdx.x * 128;
  const int h = blockIdx.y;
  __shared__ __align__(16) u16 Xs[128 * 64];
  __shared__ __align__(16) u16 Ws[3 * 64 * 64];
  const int tid = threadIdx.x;
  const int lane = tid & 63, wave = tid >> 6;
  const int q = lane & 15, g = lane >> 4;

  f32x4 acc[3][2][4];
#pragma unroll
  for (int z = 0; z < 3; ++z)
#pragma unroll
    for (int mt = 0; mt < 2; ++mt)
#pragma unroll
      for (int nt = 0; nt < 4; ++nt)
#pragma unroll
        for (int r = 0; r < 4; ++r) acc[z][mt][nt][r] = 0.f;

  for (int k0 = 0; k0 < D_; k0 += 64) {
#pragma unroll
    for (int i = 0; i < 4; ++i) {
      const int l = wave * 4 + i;
      const int chunk = l * 64 + lane;
      const int row = chunk >> 3, sb = chunk & 7;
      const int so = (sb ^ (row & 7)) * 8;
      gload16(xf + (size_t)(m0 + row) * D_ + k0 + so, &Xs[l * 512]);
    }
#pragma unroll
    for (int z = 0; z < 3; ++z)
#pragma unroll
      for (int i = 0; i < 2; ++i) {
        const int l = wave * 2 + i;
        const int chunk = l * 64 + lane;
        const int row = chunk >> 3, sb = chunk & 7;
        const int so = (sb ^ (row & 7)) * 8;
        gload16(wtf + (((size_t)z * H_ + h) * HD_ + row) * D_ + k0 + so,
                &Ws[z * 4096 + l * 512]);
      }
    __syncthreads();
#pragma unroll
    for (int ks = 0; ks < 2; ++ks) {
      f16x8 ax[2];
#pragma unroll
      for (int mt = 0; mt < 2; ++mt) {
        const int arow = wave * 32 + mt * 16 + q;
        const int ab = arow * 128 + (((g + ks * 4) ^ (arow & 7)) * 16);
        ax[mt] = *(const f16x8*)((const char*)Xs + ab);
      }
#pragma unroll
      for (int z = 0; z < 3; ++z)
#pragma unroll
        for (int nt = 0; nt < 4; ++nt) {
          const int brow = nt * 16 + q;
          const int bb =
              z * 8192 + brow * 128 + (((g + ks * 4) ^ (brow & 7)) * 16);
          f16x8 bw = *(const f16x8*)((const char*)Ws + bb);
#pragma unroll
          for (int mt = 0; mt < 2; ++mt)
            acc[z][mt][nt] = __builtin_amdgcn_mfma_f32_16x16x32_f16(
                ax[mt], bw, acc[z][mt][nt], 0, 0, 0);
        }
    }
    __syncthreads();
  }

  const int b = m0 / T_;
  const int trow0 = m0 % T_;
  const float QSC = 0.125f * 1.44269504f;  // fold log2(e) into Q
  u16* Qd = Qb + (size_t)(b * H_ + h) * T_ * HD_;
  u16* Kd = Kb + (size_t)(b * H_ + h) * T_ * HD_;
  u16* Vd = Vtb + (size_t)(b * H_ + h) * HD_ * T_;
#pragma unroll
  for (int mt = 0; mt < 2; ++mt) {
    const int t_base = trow0 + wave * 32 + mt * 16 + g * 4;
#pragma unroll
    for (int nt = 0; nt < 4; ++nt) {
      const int d = nt * 16 + q;
#pragma unroll
      for (int r = 0; r < 4; ++r) {
        Qd[(size_t)(t_base + r) * HD_ + d] = f2bf(acc[0][mt][nt][r] * QSC);
        Kd[(size_t)(t_base + r) * HD_ + d] = f2bf(acc[1][mt][nt][r]);
      }
      ushort4 v = make_ushort4(f2bf(acc[2][mt][nt][0]), f2bf(acc[2][mt][nt][1]),
                               f2bf(acc[2][mt][nt][2]), f2bf(acc[2][mt][nt][3]));
      *(ushort4*)(Vd + (size_t)d * T_ + t_base) = v;
    }
  }
}

// ---------------------------------------------------------------------------
// attn_mfma: flash attention — ROUND-4 control flow (single-buffered K/V,
// stage -> barrier -> compute -> barrier), swapped QK^T, exp2 softmax,
// cvt_pk, defer-max, ones-row PV denominator.
// Only change vs round 4: concat written as fp16 hi/lo for the 2-term oproj.
// ---------------------------------------------------------------------------
__global__ __launch_bounds__(256) void attn_mfma(
    const u16* __restrict__ Qb, const u16* __restrict__ Kb,
    const u16* __restrict__ Vtb, u16* __restrict__ ch, u16* __restrict__ cl) {
  const int q0 = blockIdx.x * 64;
  const int h = blockIdx.y;
  const int b = blockIdx.z;
  __shared__ __align__(16) u16 Ks[64 * 64];  // [key][d], XOR swizzled
  __shared__ __align__(16) u16 Vs[80 * 64];  // [hd][key]; row 64 = ones
  const int tid = threadIdx.x;
  const int lane = tid & 63, wave = tid >> 6;
  const int q = lane & 15, g = lane >> 4;

  const u16* Qg = Qb + ((size_t)(b * H_ + h) * T_ + q0 + wave * 16 + q) * HD_;
  const u16* Kg = Kb + (size_t)(b * H_ + h) * T_ * HD_;
  const u16* Vg = Vtb + (size_t)(b * H_ + h) * HD_ * T_;

  // ones-row (row 64) + zero rows 65-79, written once
  {
    u16* vext = &Vs[64 * 64];
    for (int i = tid; i < 16 * 64; i += 256) vext[i] = (i < 64) ? 0x3F80 : 0;
  }

  const bf16x8 qf0 = *(const bf16x8*)(Qg + g * 8);
  const bf16x8 qf1 = *(const bf16x8*)(Qg + 32 + g * 8);

  f32x4 ot[4], ot4;
#pragma unroll
  for (int t = 0; t < 4; ++t)
#pragma unroll
    for (int r = 0; r < 4; ++r) ot[t][r] = 0.f;
#pragma unroll
  for (int r = 0; r < 4; ++r) ot4[r] = 0.f;
  float m_run = -INFINITY;

  for (int kt = 0; kt < T_; kt += 64) {
#pragma unroll
    for (int c = 0; c < 2; ++c) {
      const int cc = wave * 2 + c;
      const int slot = cc * 64 + lane;
      const int row = slot >> 3, sb = slot & 7;
      const int so = (sb ^ (row & 7)) * 8;
      gload16(Kg + (size_t)(kt + row) * HD_ + so, &Ks[cc * 512]);
      gload16(Vg + (size_t)row * T_ + kt + so, &Vs[cc * 512]);
    }
    __syncthreads();

    // S^T (log2 domain; Q pre-scaled by log2e/8)
    f32x4 st[4];
#pragma unroll
    for (int t = 0; t < 4; ++t)
#pragma unroll
      for (int r = 0; r < 4; ++r) st[t][r] = 0.f;
#pragma unroll
    for (int ks = 0; ks < 2; ++ks) {
      const bf16x8 qf = ks ? qf1 : qf0;
#pragma unroll
      for (int t = 0; t < 4; ++t) {
        const int row = t * 16 + q;
        const int byte = row * 128 + (((g + ks * 4) ^ (row & 7)) * 16);
        bf16x8 kf = *(const bf16x8*)((const char*)Ks + byte);
        st[t] = __builtin_amdgcn_mfma_f32_16x16x32_bf16(kf, qf, st[t], 0, 0, 0);
      }
    }

    // online softmax, exp2 domain, defer-max
    float mx = st[0][0];
#pragma unroll
    for (int t = 0; t < 4; ++t)
#pragma unroll
      for (int r = 0; r < 4; ++r) mx = fmaxf(mx, st[t][r]);
    mx = fmaxf(mx, __shfl_xor(mx, 16));
    mx = fmaxf(mx, __shfl_xor(mx, 32));
    if (!__all(mx <= m_run + 8.f)) {
      const float mnew = fmaxf(m_run, mx);
      const float al = __builtin_amdgcn_exp2f(m_run - mnew);
      m_run = mnew;
#pragma unroll
      for (int t = 0; t < 4; ++t)
#pragma unroll
        for (int r = 0; r < 4; ++r) ot[t][r] *= al;
#pragma unroll
      for (int r = 0; r < 4; ++r) ot4[r] *= al;
    }
    u32 pk[4][2];
#pragma unroll
    for (int t = 0; t < 4; ++t) {
      const float p0 = __builtin_amdgcn_exp2f(st[t][0] - m_run);
      const float p1 = __builtin_amdgcn_exp2f(st[t][1] - m_run);
      const float p2 = __builtin_amdgcn_exp2f(st[t][2] - m_run);
      const float p3 = __builtin_amdgcn_exp2f(st[t][3] - m_run);
      pk[t][0] = cvtpk(p0, p1);
      pk[t][1] = cvtpk(p2, p3);
    }

    // PV: O^T += V^T * P^T  (+ ones-row tile accumulating sum(P))
#pragma unroll
    for (int ks = 0; ks < 2; ++ks) {
      u32 bw[4];
#pragma unroll
      for (int w = 0; w < 4; ++w) {
        const int srcl = ((2 * g + (w >> 1)) & 3) * 16 + q;
        const u32 lo = (u32)__shfl((int)pk[ks * 2][w & 1], srcl);
        const u32 hi2 = (u32)__shfl((int)pk[ks * 2 + 1][w & 1], srcl);
        bw[w] = (g >> 1) ? hi2 : lo;
      }
      u32x4 tmp = {bw[0], bw[1], bw[2], bw[3]};
      bf16x8 pf = __builtin_bit_cast(bf16x8, tmp);
#pragma unroll
      for (int t = 0; t < 4; ++t) {
        const int row = t * 16 + q;
        const int byte = row * 128 + (((g + ks * 4) ^ (row & 7)) * 16);
        bf16x8 vf = *(const bf16x8*)((const char*)Vs + byte);
        ot[t] = __builtin_amdgcn_mfma_f32_16x16x32_bf16(vf, pf, ot[t], 0, 0, 0);
      }
      {
        const int row = 64 + q;
        const int byte = row * 128 + (((g + ks * 4) ^ (row & 7)) * 16);
        bf16x8 vf = *(const bf16x8*)((const char*)Vs + byte);
        ot4 = __builtin_amdgcn_mfma_f32_16x16x32_bf16(vf, pf, ot4, 0, 0, 0);
      }
    }
    __syncthreads();  // protect Ks/Vs before next tile's staging
  }

  // l for q-row q sits in lane q (ones-tile row 0, reg 0)
  const float lsum = __shfl(ot4[0], q);
  const float inv = 1.f / lsum;
  const size_t rowbase = (size_t)(b * T_ + q0 + wave * 16 + q) * D_ + h * HD_;
#pragma unroll
  for (int t = 0; t < 4; ++t) {
    float v0 = ot[t][0] * inv, v1 = ot[t][1] * inv;
    float v2 = ot[t][2] * inv, v3 = ot[t][3] * inv;
    ushort4 vh = make_ushort4(f2h(v0), f2h(v1), f2h(v2), f2h(v3));
    ushort4 vl =
        make_ushort4(f2h(v0 - h2f(vh.x)), f2h(v1 - h2f(vh.y)),
                     f2h(v2 - h2f(vh.z)), f2h(v3 - h2f(vh.w)));
    *(ushort4*)(ch + rowbase + t * 16 + g * 4) = vh;
    *(ushort4*)(cl + rowbase + t * 16 + g * 4) = vl;
  }
}

// ---------------------------------------------------------------------------
// oproj_mfma: 2-term fp16 (c_hi*W + c_lo*W), 128x128 tile.  grid (64, 8).
// ---------------------------------------------------------------------------
__global__ __launch_bounds__(256, 2) void oproj_mfma(
    const u16* __restrict__ ch_g, const u16* __restrict__ cl_g,
    const u16* __restrict__ wo_g, float* __restrict__ out) {
  const int m0 = blockIdx.x * 128;
  const int n0 = blockIdx.y * 128;
  __shared__ __align__(16) u16 Ah[128 * 64];
  __shared__ __align__(16) u16 Al[128 * 64];
  __shared__ __align__(16) u16 Bs[128 * 64];
  const int tid = threadIdx.x;
  const int lane = tid & 63, wave = tid >> 6;
  const int q = lane & 15, g = lane >> 4;

  f32x4 acc[2][8];
#pragma unroll
  for (int mt = 0; mt < 2; ++mt)
#pragma unroll
    for (int nt = 0; nt < 8; ++nt)
#pragma unroll
      for (int r = 0; r < 4; ++r) acc[mt][nt][r] = 0.f;

  for (int k0 = 0; k0 < D_; k0 += 64) {
#pragma unroll
    for (int i = 0; i < 4; ++i) {
      const int l = wave * 4 + i;
      const int chunk = l * 64 + lane;
      const int row = chunk >> 3, sb = chunk & 7;
      const int so = (sb ^ (row & 7)) * 8;
      const size_t ga = (size_t)(m0 + row) * D_ + k0 + so;
      const size_t gb = (size_t)(n0 + row) * D_ + k0 + so;
      gload16(ch_g + ga, &Ah[l * 512]);
      gload16(cl_g + ga, &Al[l * 512]);
      gload16(wo_g + gb, &Bs[l * 512]);
    }
    __syncthreads();
#pragma unroll
    for (int ks = 0; ks < 2; ++ks) {
      f16x8 axh[2], axl[2];
#pragma unroll
      for (int mt = 0; mt < 2; ++mt) {
        const int arow = wave * 32 + mt * 16 + q;
        const int ab = arow * 128 + (((g + ks * 4) ^ (arow & 7)) * 16);
        axh[mt] = *(const f16x8*)((const char*)Ah + ab);
        axl[mt] = *(const f16x8*)((const char*)Al + ab);
      }
#pragma unroll
      for (int nt = 0; nt < 8; ++nt) {
        const int brow = nt * 16 + q;
        const int bb = brow * 128 + (((g + ks * 4) ^ (brow & 7)) * 16);
        f16x8 bw = *(const f16x8*)((const char*)Bs + bb);
#pragma unroll
        for (int mt = 0; mt < 2; ++mt) {
          acc[mt][nt] = __builtin_amdgcn_mfma_f32_16x16x32_f16(
              axh[mt], bw, acc[mt][nt], 0, 0, 0);
          acc[mt][nt] = __builtin_amdgcn_mfma_f32_16x16x32_f16(
              axl[mt], bw, acc[mt][nt], 0, 0, 0);
        }
      }
    }
    __syncthreads();
  }

#pragma unroll
  for (int mt = 0; mt < 2; ++mt) {
    const int mrow = m0 + wave * 32 + mt * 16 + g * 4;
#pragma unroll
    for (int nt = 0; nt < 8; ++nt)
#pragma unroll
      for (int r = 0; r < 4; ++r)
        out[(size_t)(mrow + r) * D_ + n0 + nt * 16 + q] = acc[mt][nt][r];
  }
}

// ---------------------------------------------------------------------------
extern "C" void kernel_launch(void* const* d_in, const int* in_sizes, int n_in,
                              void* d_out, int out_size, void* d_ws,
                              size_t ws_size, hipStream_t stream) {
  const float* x = (const float*)d_in[0];
  const float* Wq = (const float*)d_in[1];
  const float* Wk = (const float*)d_in[2];
  const float* Wv = (const float*)d_in[3];
  const float* Wo = (const float*)d_in[4];
  float* out = (float*)d_out;

  u16* ws16 = (u16*)d_ws;
  u16* xf   = ws16;                 //  8,388,608 (fp16 x)
  u16* wtf  = ws16 + 8388608;       //  3,145,728 (fp16 W^T, z-stacked)
  u16* wof  = ws16 + 11534336;      //  1,048,576 (fp16 Wo)
  u16* Qb   = ws16 + 12582912;      //  8,388,608 (bf16)
  u16* Kb   = ws16 + 20971520;      //  8,388,608 (bf16)
  u16* Vtb  = ws16 + 29360128;      //  8,388,608 (bf16, transposed)
  u16* c_lo = ws16 + 37748736;      //  8,388,608 (fp16)
  u16* c_hi = xf;                   //  reuse (x consumed before attn)

  convert_f16<<<2048, 256, 0, stream>>>(x, xf, BT_ * D_ / 4);
  convert_f16<<<1024, 256, 0, stream>>>(Wo, wof, D_ * D_ / 4);
  convert_wt<<<dim3(D_ / 64, H_, 3), 256, 0, stream>>>(Wq, Wk, Wv, wtf);
  qkv_mfma<<<dim3(BT_ / 128, H_), 256, 0, stream>>>(xf, wtf, Qb, Kb, Vtb);
  attn_mfma<<<dim3(T_ / 64, H_, B_), 256, 0, stream>>>(Qb, Kb, Vtb, c_hi, c_lo);
  oproj_mfma<<<dim3(BT_ / 128, D_ / 128), 256, 0, stream>>>(c_hi, c_lo, wof,
                                                            out);
}